// Round 6
// baseline (34.405 us; speedup 1.0000x reference)
//
#include <hip/hip_runtime.h>
#include <math.h>

// Chamfer loss, B=8, N=M=4096, D=3, fp32. Single compute kernel.
// 256 blocks = (dir, batch, 256-query chunk), T=512.
// Full 4096-pt target cloud staged in LDS as (t0,t1,t2,|t|^2) [64 KB].
// Thread (qrow=tid&31, slice=tid>>5): 8 queries, scans 256-target slice;
// each ds_read_b128 feeds 32 VALU ops -> VALU-bound.
// d' = |t|^2 - 2 q.t ; |q|^2 + clamp deferred past the cross-slice min.
// Finish: per-block weighted sum -> ONE packed 64-bit atomicAdd
//   add = (1<<56) | fix44(sum). Counter rides in the high byte; the block
//   that sees old>>56==255 owns the grand total (old+add) and writes d_out.
//   No fences needed (data travels in the atomic); integer sum is
//   order-independent -> deterministic. ws[0..7] zeroed via memset node.

constexpr int BATCH = 8;
constexpr int NP    = 4096;   // points per cloud
constexpr int T     = 512;    // threads per block (8 waves)
constexpr int QPB   = 256;    // queries per block
constexpr int KPT   = 8;      // queries per thread
constexpr int S     = 16;     // target slices (threads per query column)
constexpr int TPS   = 256;    // targets per slice
constexpr int NBLK  = 256;

__global__ __launch_bounds__(T) void chamfer_main(
    const float* __restrict__ x, const float* __restrict__ y,
    const float* __restrict__ w, unsigned long long* __restrict__ acc,
    float* __restrict__ out)
{
    const int bid = blockIdx.x;          // dir(1b) | b(3b) | qc(4b)
    const int dir = bid >> 7;
    const int b   = (bid >> 4) & 7;
    const int qc  = bid & 15;

    const float* q = dir ? y : x;
    const float* t = dir ? x : y;

    __shared__ float4 ty[NP];            // 64 KB target stage
    __shared__ float  pmin[S / 2][QPB];  // 8 KB cross-slice-pair mins
    __shared__ float  qn[QPB];           // |q|^2 per query
    __shared__ float  rsum[8];

    const int tid = threadIdx.x;

    // stage all 4096 targets of batch b (coalesced 12B/thread reads)
    const float* tb = t + (size_t)b * NP * 3;
    for (int j = tid; j < NP; j += T) {
        float t0 = tb[3 * j + 0];
        float t1 = tb[3 * j + 1];
        float t2 = tb[3 * j + 2];
        ty[j] = make_float4(t0, t1, t2, fmaf(t0, t0, fmaf(t1, t1, t2 * t2)));
    }

    // this thread's 8 queries (24 consecutive floats, 16B-aligned)
    const int qrow  = tid & 31;
    const int slice = tid >> 5;
    const int n0 = b * NP + qc * QPB + qrow * KPT;
    const float4* qb = reinterpret_cast<const float4*>(q + (size_t)n0 * 3);
    float4 v0 = qb[0], v1 = qb[1], v2 = qb[2], v3 = qb[3], v4 = qb[4], v5 = qb[5];
    float px[KPT][3] = {
        {v0.x, v0.y, v0.z}, {v0.w, v1.x, v1.y},
        {v1.z, v1.w, v2.x}, {v2.y, v2.z, v2.w},
        {v3.x, v3.y, v3.z}, {v3.w, v4.x, v4.y},
        {v4.z, v4.w, v5.x}, {v5.y, v5.z, v5.w},
    };
    float xn[KPT][3], mn[KPT];
    #pragma unroll
    for (int k = 0; k < KPT; ++k) {
        float x2 = fmaf(px[k][0], px[k][0],
                   fmaf(px[k][1], px[k][1], px[k][2] * px[k][2]));
        if (slice == 0) qn[qrow * KPT + k] = x2;
        #pragma unroll
        for (int d = 0; d < 3; ++d) xn[k][d] = -2.0f * px[k][d];
        mn[k] = INFINITY;
    }

    __syncthreads();

    // min over this slice's targets of d' = |t|^2 - 2 q.t
    const int j0 = slice * TPS;
    #pragma unroll 4
    for (int j = j0; j < j0 + TPS; j += 2) {
        float4 ta = ty[j];               // <=2 distinct addrs per wave (free)
        float4 tc = ty[j + 1];
        #pragma unroll
        for (int k = 0; k < KPT; ++k) {
            float da = fmaf(xn[k][0], ta.x,
                       fmaf(xn[k][1], ta.y, fmaf(xn[k][2], ta.z, ta.w)));
            float db = fmaf(xn[k][0], tc.x,
                       fmaf(xn[k][1], tc.y, fmaf(xn[k][2], tc.z, tc.w)));
            mn[k] = fminf(mn[k], fminf(da, db));   // -> v_min3_f32
        }
    }

    // intra-wave combine of slice pairs (lanes l <-> l+32), then exchange
    #pragma unroll
    for (int k = 0; k < KPT; ++k)
        mn[k] = fminf(mn[k], __shfl_xor(mn[k], 32, 64));
    if ((slice & 1) == 0) {
        #pragma unroll
        for (int k = 0; k < KPT; ++k)
            pmin[slice >> 1][qrow * KPT + k] = mn[k];
    }
    __syncthreads();

    float val = 0.0f;
    if (tid < QPB) {                     // thread tid owns query tid
        float m = pmin[0][tid];
        #pragma unroll
        for (int s = 1; s < S / 2; ++s) m = fminf(m, pmin[s][tid]);
        val = fmaxf(qn[tid] + m, 0.0f);  // clamp after full min
    }

    // fixed-order block sum (other waves contribute 0)
    for (int off = 32; off; off >>= 1) val += __shfl_down(val, off, 64);
    if ((tid & 63) == 0) rsum[tid >> 6] = val;
    __syncthreads();
    if (tid == 0) {
        float s = ((rsum[0] + rsum[1]) + (rsum[2] + rsum[3]))
                + ((rsum[4] + rsum[5]) + (rsum[6] + rsum[7]));
        s *= w[b] * (1.0f / ((float)NP * (float)BATCH));
        // fixed-point 2^44, positive by construction
        unsigned long long fx =
            (unsigned long long)llrintf(s * 17592186044416.0f);
        unsigned long long add = (1ULL << 56) | fx;
        unsigned long long old = atomicAdd(acc, add);   // device scope
        if ((old >> 56) == (unsigned long long)(NBLK - 1)) {
            unsigned long long total = old + add;
            double sum = (double)(total & ((1ULL << 56) - 1));
            out[0] = (float)(sum * (1.0 / 17592186044416.0));
        }
    }
}

extern "C" void kernel_launch(void* const* d_in, const int* in_sizes, int n_in,
                              void* d_out, int out_size, void* d_ws, size_t ws_size,
                              hipStream_t stream) {
    const float* x = (const float*)d_in[0];   // (8, 4096, 3)
    const float* y = (const float*)d_in[1];   // (8, 4096, 3)
    const float* w = (const float*)d_in[2];   // (8,)
    float* out = (float*)d_out;
    unsigned long long* acc = (unsigned long long*)d_ws;

    hipMemsetAsync(acc, 0, sizeof(unsigned long long), stream);
    chamfer_main<<<NBLK, T, 0, stream>>>(x, y, w, acc, out);
}

// Round 7
// 26.880 us; speedup vs baseline: 1.2800x; 1.2800x over previous
//
#include <hip/hip_runtime.h>
#include <math.h>

// Chamfer loss, B=8, N=M=4096, D=3, fp32. Two kernels (round-5 structure).
// k1: 256 blocks = (dir, batch, 256-query chunk), T=1024 (16 waves -> 4/SIMD).
//     Full 4096-pt target cloud staged in LDS as (t0,t1,t2,|t|^2) [64 KB].
//     Thread (qrow=tid&31, slice=tid>>5): 8 queries, scans 128-target slice.
//     Wave = 2 slices -> ds_read_b128 has 2 distinct addrs (free, m136).
//     d' = |t|^2 - 2 q.t ; v_min3_f32 folds the pair-min (3.5 ops/pair).
//     |q|^2 + clamp deferred past the cross-slice min.
// k2: single block sums the 256 weighted per-block partials.

constexpr int BATCH = 8;
constexpr int NP    = 4096;   // points per cloud
constexpr int T     = 1024;   // threads per block (16 waves, 4/SIMD)
constexpr int QPB   = 256;    // queries per block
constexpr int KPT   = 8;      // queries per thread
constexpr int S     = 32;     // target slices (threads per query column)
constexpr int TPS   = 128;    // targets per slice

__global__ __launch_bounds__(T, 4) void chamfer_main(
    const float* __restrict__ x, const float* __restrict__ y,
    const float* __restrict__ w, float* __restrict__ ps)
{
    const int bid = blockIdx.x;          // dir(1b) | b(3b) | qc(4b)
    const int dir = bid >> 7;
    const int b   = (bid >> 4) & 7;
    const int qc  = bid & 15;

    const float* q = dir ? y : x;
    const float* t = dir ? x : y;

    __shared__ float4 ty[NP];            // 64 KB target stage
    __shared__ float  pmin[S / 2][QPB];  // 16 KB cross-slice-pair mins
    __shared__ float  qn[QPB];           // |q|^2 per query
    __shared__ float  rsum[T / 64];

    const int tid = threadIdx.x;

    // stage all 4096 targets of batch b (coalesced 12B/thread reads)
    const float* tb = t + (size_t)b * NP * 3;
    for (int j = tid; j < NP; j += T) {
        float t0 = tb[3 * j + 0];
        float t1 = tb[3 * j + 1];
        float t2 = tb[3 * j + 2];
        ty[j] = make_float4(t0, t1, t2, fmaf(t0, t0, fmaf(t1, t1, t2 * t2)));
    }

    // this thread's 8 queries (24 consecutive floats, 16B-aligned)
    const int qrow  = tid & 31;
    const int slice = tid >> 5;          // [0,32); wave = slices {2w, 2w+1}
    const int n0 = b * NP + qc * QPB + qrow * KPT;
    const float4* qb = reinterpret_cast<const float4*>(q + (size_t)n0 * 3);
    float4 v0 = qb[0], v1 = qb[1], v2 = qb[2], v3 = qb[3], v4 = qb[4], v5 = qb[5];
    float px[KPT][3] = {
        {v0.x, v0.y, v0.z}, {v0.w, v1.x, v1.y},
        {v1.z, v1.w, v2.x}, {v2.y, v2.z, v2.w},
        {v3.x, v3.y, v3.z}, {v3.w, v4.x, v4.y},
        {v4.z, v4.w, v5.x}, {v5.y, v5.z, v5.w},
    };
    float xn[KPT][3], mn[KPT];
    #pragma unroll
    for (int k = 0; k < KPT; ++k) {
        float x2 = fmaf(px[k][0], px[k][0],
                   fmaf(px[k][1], px[k][1], px[k][2] * px[k][2]));
        if (slice == 0) qn[qrow * KPT + k] = x2;
        #pragma unroll
        for (int d = 0; d < 3; ++d) xn[k][d] = -2.0f * px[k][d];
        mn[k] = INFINITY;
    }

    __syncthreads();

    // min over this slice's targets of d' = |t|^2 - 2 q.t
    const int j0 = slice * TPS;
    #pragma unroll 4
    for (int j = j0; j < j0 + TPS; j += 2) {
        float4 ta = ty[j];               // 2 distinct addrs per wave (free)
        float4 tc = ty[j + 1];
        #pragma unroll
        for (int k = 0; k < KPT; ++k) {
            float da = fmaf(xn[k][0], ta.x,
                       fmaf(xn[k][1], ta.y, fmaf(xn[k][2], ta.z, ta.w)));
            float db = fmaf(xn[k][0], tc.x,
                       fmaf(xn[k][1], tc.y, fmaf(xn[k][2], tc.z, tc.w)));
            float m;
            asm("v_min3_f32 %0, %1, %2, %3"
                : "=v"(m) : "v"(mn[k]), "v"(da), "v"(db));
            mn[k] = m;                   // 3.5 VALU ops per pair
        }
    }

    // intra-wave combine of slice pairs (lanes l <-> l+32), then exchange
    #pragma unroll
    for (int k = 0; k < KPT; ++k)
        mn[k] = fminf(mn[k], __shfl_xor(mn[k], 32, 64));
    if ((slice & 1) == 0) {
        #pragma unroll
        for (int k = 0; k < KPT; ++k)
            pmin[slice >> 1][qrow * KPT + k] = mn[k];
    }
    __syncthreads();

    float val = 0.0f;
    if (tid < QPB) {                     // thread tid owns query tid
        float m = pmin[0][tid];
        #pragma unroll
        for (int s = 1; s < S / 2; ++s) m = fminf(m, pmin[s][tid]);
        val = fmaxf(qn[tid] + m, 0.0f);  // clamp after full min
    }

    // fixed-order block sum (other waves contribute 0)
    for (int off = 32; off; off >>= 1) val += __shfl_down(val, off, 64);
    if ((tid & 63) == 0) rsum[tid >> 6] = val;
    __syncthreads();
    if (tid == 0) {
        float s = 0.0f;
        #pragma unroll
        for (int i = 0; i < T / 64; ++i) s += rsum[i];
        ps[bid] = s * w[b] * (1.0f / ((float)NP * (float)BATCH));
    }
}

__global__ __launch_bounds__(256) void chamfer_final(
    const float* __restrict__ ps, float* __restrict__ out)
{
    const int tid = threadIdx.x;         // 256 threads
    float v = ps[tid];
    for (int off = 32; off; off >>= 1) v += __shfl_down(v, off, 64);
    __shared__ float red[4];
    if ((tid & 63) == 0) red[tid >> 6] = v;
    __syncthreads();
    if (tid == 0) out[0] = (red[0] + red[1]) + (red[2] + red[3]);
}

extern "C" void kernel_launch(void* const* d_in, const int* in_sizes, int n_in,
                              void* d_out, int out_size, void* d_ws, size_t ws_size,
                              hipStream_t stream) {
    const float* x = (const float*)d_in[0];   // (8, 4096, 3)
    const float* y = (const float*)d_in[1];   // (8, 4096, 3)
    const float* w = (const float*)d_in[2];   // (8,)
    float* out = (float*)d_out;
    float* ps  = (float*)d_ws;                // 256 floats

    chamfer_main<<<256, T, 0, stream>>>(x, y, w, ps);
    chamfer_final<<<1, 256, 0, stream>>>(ps, out);
}